// Round 18
// baseline (103.689 us; speedup 1.0000x reference)
//
#include <hip/hip_runtime.h>
#include <cstdint>
#include <cstddef>

#define B_DIM 8
#define L_DIM 33600
#define N_DIM 128
#define C_DIM 80
#define K_TOP 13
#define EPS_F 1e-9f
#define NCH2 66       // ceil(L_DIM/512): 512-anchor chunks (2 anchors/thread)
#define SEGSZ 32      // per-(bn,chunk) iou>0 entries
#define WBUF 352      // per-wave candidate buffer (max bn iou>0 ~270 +10sigma)
#define PLCAP 16384   // positives list capacity (max true positives 9984)

typedef float f32x4 __attribute__((ext_vector_type(4)));

// Bit-exact replica of the reference IoU (f32, no FMA contraction, same op order).
__device__ __forceinline__ float iou_pair(float g0, float g1, float g2, float g3,
                                          float p0, float p1, float p2, float p3) {
    float ltx = fmaxf(g0, p0), lty = fmaxf(g1, p1);
    float rbx = fminf(g2, p2), rby = fminf(g3, p3);
    float wx = fmaxf(__fsub_rn(rbx, ltx), 0.0f);
    float wy = fmaxf(__fsub_rn(rby, lty), 0.0f);
    float inter = __fmul_rn(wx, wy);
    float ag = __fmul_rn(__fsub_rn(g2, g0), __fsub_rn(g3, g1));
    float ap = __fmul_rn(__fsub_rn(p2, p0), __fsub_rn(p3, p1));
    float den = __fadd_rn(__fsub_rn(__fadd_rn(ag, ap), inter), EPS_F);
    float iou = __fdiv_rn(inter, den);
    if (iou > 1.0f) iou = 0.0f;            // (1.0 + 1e-9) rounds to 1.0f in f32
    iou = fminf(fmaxf(iou, 0.0f), 1.0f);
    return iou;
}

// Sortable key: (truncated double bits of s>=0) | (0xFFFF - l) in low 16.
__device__ __forceinline__ unsigned long long make_key(double s, int l) {
    unsigned long long sb = (unsigned long long)__double_as_longlong(s);
    return (sb & 0xFFFFFFFFFFFF0000ull) | (unsigned long long)(0xFFFF - l);
}

__device__ __forceinline__ void nt_store4(float4 v, float4* p) {
    __builtin_nontemporal_store(*(f32x4*)&v, (f32x4*)p);
}

// K_push: 2 anchors/thread; padded GTs as inverted boxes; zeroes posbits
// slots + maxal/maxio + positives counter; single-walk segmented scatter of
// iou>0 keys; PLUS grid-strided NT zero-fill of the 86MB out_sc (bulk of the
// scores output is zeros — the ~10k nonzeros are scattered later by k_out).
__global__ __launch_bounds__(256) void k_push(
    const float* __restrict__ pts, const float* __restrict__ pbox,
    const float* __restrict__ gbox, const float* __restrict__ gpad,
    const int* __restrict__ glbl, const float* __restrict__ psc,
    int* __restrict__ scount, unsigned long long* __restrict__ bucket,
    ulonglong2* __restrict__ posb2,
    float* __restrict__ maxal, float* __restrict__ maxio,
    int* __restrict__ pcount, float* __restrict__ out_sc)
{
    const int chunk = blockIdx.x, b = blockIdx.y, t = threadIdx.x;
    __shared__ float4 gb[N_DIM];
    __shared__ int    gli[N_DIM];
    __shared__ int    lcnt[N_DIM];
    if (t < N_DIM) {
        float4 g = reinterpret_cast<const float4*>(gbox)[(size_t)b * N_DIM + t];
        if (gpad[b * N_DIM + t] <= 0.0f) g = make_float4(3e38f, 3e38f, -3e38f, -3e38f);
        gb[t] = g;
        gli[t] = min(max(glbl[b * N_DIM + t], 0), C_DIM - 1);
        lcnt[t] = 0;
        if (chunk == 0) { maxal[b * N_DIM + t] = 0.0f; maxio[b * N_DIM + t] = 0.0f; }
    }
    if (chunk == 0 && b == 0 && t == 0) *pcount = 0;
    __syncthreads();

    const float* psb = psc + (size_t)b * L_DIM * C_DIM;
    const float4* pbb = reinterpret_cast<const float4*>(pbox) + (size_t)b * L_DIM;
    const int l0 = chunk * 512 + t, l1 = l0 + 256;
    const bool v0 = (l0 < L_DIM), v1 = (l1 < L_DIM);
    float a0x = -3e38f, a0y = -3e38f, a1x = -3e38f, a1y = -3e38f;
    float4 pb0 = make_float4(0, 0, 0, 0), pb1 = make_float4(0, 0, 0, 0);
    if (v0) {
        posb2[(size_t)b * L_DIM + l0] = make_ulonglong2(0ull, 0ull);
        const float2 ap = reinterpret_cast<const float2*>(pts)[l0];
        a0x = ap.x; a0y = ap.y;
        pb0 = pbb[l0];                        // coalesced float4
    }
    if (v1) {
        posb2[(size_t)b * L_DIM + l1] = make_ulonglong2(0ull, 0ull);
        const float2 ap = reinterpret_cast<const float2*>(pts)[l1];
        a1x = ap.x; a1y = ap.y;
        pb1 = pbb[l1];
    }

    unsigned long long m0a = 0ull, m1a = 0ull, m0b = 0ull, m1b = 0ull;
    for (int n = 0; n < N_DIM; ++n) {
        const float4 g = gb[n];
        bool i0 = (a0x >= g.x && a0x <= g.z && a0y >= g.y && a0y <= g.w);
        bool i1 = (a1x >= g.x && a1x <= g.z && a1y >= g.y && a1y <= g.w);
        if (n < 64) { m0a |= i0 ? (1ull << n) : 0ull;        m0b |= i1 ? (1ull << n) : 0ull; }
        else        { m1a |= i0 ? (1ull << (n - 64)) : 0ull; m1b |= i1 ? (1ull << (n - 64)) : 0ull; }
    }

    const size_t segbase = ((size_t)(b * N_DIM) * NCH2 + chunk) * SEGSZ;
    if (v0 && l0 >= 32) {                      // l<32 are unconditional seeds downstream
        unsigned long long m = m0a;
        while (m) {
            int n = __ffsll((long long)m) - 1; m &= m - 1;
            const float4 g = gb[n];
            float iou = iou_pair(g.x, g.y, g.z, g.w, pb0.x, pb0.y, pb0.z, pb0.w);
            if (iou > 0.0f) {
                float cs = psb[(size_t)l0 * C_DIM + gli[n]];
                double d = (double)iou, d2 = d * d;
                unsigned long long key = make_key((double)cs * (d2 * d2 * d2), l0);
                int pos = atomicAdd(&lcnt[n], 1);
                if (pos < SEGSZ) bucket[segbase + (size_t)n * NCH2 * SEGSZ + pos] = key;
            }
        }
        m = m1a;
        while (m) {
            int n = __ffsll((long long)m) - 1; m &= m - 1;
            const float4 g = gb[n + 64];
            float iou = iou_pair(g.x, g.y, g.z, g.w, pb0.x, pb0.y, pb0.z, pb0.w);
            if (iou > 0.0f) {
                float cs = psb[(size_t)l0 * C_DIM + gli[n + 64]];
                double d = (double)iou, d2 = d * d;
                unsigned long long key = make_key((double)cs * (d2 * d2 * d2), l0);
                int pos = atomicAdd(&lcnt[n + 64], 1);
                if (pos < SEGSZ) bucket[segbase + (size_t)(n + 64) * NCH2 * SEGSZ + pos] = key;
            }
        }
    }
    if (v1) {                                  // l1 >= 256 always
        unsigned long long m = m0b;
        while (m) {
            int n = __ffsll((long long)m) - 1; m &= m - 1;
            const float4 g = gb[n];
            float iou = iou_pair(g.x, g.y, g.z, g.w, pb1.x, pb1.y, pb1.z, pb1.w);
            if (iou > 0.0f) {
                float cs = psb[(size_t)l1 * C_DIM + gli[n]];
                double d = (double)iou, d2 = d * d;
                unsigned long long key = make_key((double)cs * (d2 * d2 * d2), l1);
                int pos = atomicAdd(&lcnt[n], 1);
                if (pos < SEGSZ) bucket[segbase + (size_t)n * NCH2 * SEGSZ + pos] = key;
            }
        }
        m = m1b;
        while (m) {
            int n = __ffsll((long long)m) - 1; m &= m - 1;
            const float4 g = gb[n + 64];
            float iou = iou_pair(g.x, g.y, g.z, g.w, pb1.x, pb1.y, pb1.z, pb1.w);
            if (iou > 0.0f) {
                float cs = psb[(size_t)l1 * C_DIM + gli[n + 64]];
                double d = (double)iou, d2 = d * d;
                unsigned long long key = make_key((double)cs * (d2 * d2 * d2), l1);
                int pos = atomicAdd(&lcnt[n + 64], 1);
                if (pos < SEGSZ) bucket[segbase + (size_t)(n + 64) * NCH2 * SEGSZ + pos] = key;
            }
        }
    }
    __syncthreads();

    if (t < N_DIM)                             // counts written every call (no zeroing)
        scount[(b * N_DIM + t) * NCH2 + chunk] = min(lcnt[t], SEGSZ);

    // bulk zero-fill of out_sc (86MB), NT float4, grid-strided over all threads
    {
        const float4 z = make_float4(0.0f, 0.0f, 0.0f, 0.0f);
        float4* o4 = reinterpret_cast<float4*>(out_sc);
        const size_t TOT4 = (size_t)B_DIM * L_DIM * (C_DIM / 4);  // 5,376,000
        const size_t stride = (size_t)NCH2 * B_DIM * 256;         // 135,168
        for (size_t i = (size_t)(b * NCH2 + chunk) * 256 + t; i < TOT4; i += stride)
            nt_store4(z, &o4[i]);
    }
}

// K_top13: ONE WAVE per (b,n), 4 bn per 256-thread block, grid 256.
// Compact this bn's ~27 segment entries into a per-wave LDS buffer, then
// per-lane 13-deep lists + 13-round 64-lane butterfly; lane 0 atomicOr.
__global__ __launch_bounds__(256) void k_top13(
    const float* __restrict__ psc, const float* __restrict__ pbox,
    const float* __restrict__ pts, const int* __restrict__ glbl,
    const float* __restrict__ gbox, const float* __restrict__ gpad,
    const int* __restrict__ scount, const unsigned long long* __restrict__ bucket,
    unsigned long long* __restrict__ posbits)
{
    const int t = threadIdx.x, lane = t & 63, wid = t >> 6;
    const int bn = blockIdx.x * 4 + wid;        // grid 256 -> bn 0..1023
    const int b = bn >> 7, n = bn & 127;
    const bool active = (gpad[b * N_DIM + n] > 0.0f);

    __shared__ unsigned long long buf[4][WBUF];
    __shared__ int wq[4];
    if (lane == 0) wq[wid] = 0;
    __builtin_amdgcn_wave_barrier();

    if (active) {                               // phase 1: compact segments
        for (int s = lane; s < NCH2; s += 64) {
            int c = scount[bn * NCH2 + s];
            if (c > 0) {
                int pos = atomicAdd(&wq[wid], c);
                const unsigned long long* seg = bucket + ((size_t)bn * NCH2 + s) * SEGSZ;
                for (int j = 0; j < c; ++j)
                    if (pos + j < WBUF) buf[wid][pos + j] = seg[j];
            }
        }
    }
    __syncthreads();                            // all waves participate exactly once
    if (!active) return;

    const int nc = min(wq[wid], WBUF);
    const float g0 = gbox[(b * N_DIM + n) * 4 + 0];
    const float g1 = gbox[(b * N_DIM + n) * 4 + 1];
    const float g2 = gbox[(b * N_DIM + n) * 4 + 2];
    const float g3 = gbox[(b * N_DIM + n) * 4 + 3];
    int lbl = glbl[b * N_DIM + n];
    lbl = min(max(lbl, 0), C_DIM - 1);
    const float* psb = psc + (size_t)b * L_DIM * C_DIM;
    const float* pbb = pbox + (size_t)b * L_DIM * 4;

    unsigned long long key[K_TOP];
    #pragma unroll
    for (int k = 0; k < K_TOP; ++k) key[k] = 0ull;

    // seed candidate (lane < 32): full scoring path for l = lane
    if (lane < 32) {
        const int l = lane;
        const float2 ap = reinterpret_cast<const float2*>(pts)[l];
        unsigned long long ck = (unsigned long long)(0xFFFF - l);
        if (ap.x >= g0 && ap.x <= g2 && ap.y >= g1 && ap.y <= g3) {
            const float4 pbv = reinterpret_cast<const float4*>(pbb)[l];
            float iou = iou_pair(g0, g1, g2, g3, pbv.x, pbv.y, pbv.z, pbv.w);
            if (iou > 0.0f) {
                float cs = psb[(size_t)l * C_DIM + lbl];
                double d = (double)iou, d2 = d * d;
                ck = make_key((double)cs * (d2 * d2 * d2), l);
            }
        }
        key[0] = ck;                            // list was empty; sorted trivially
    }
    // bucket candidates: one per lane per pass (~27 total -> 1 pass typical)
    for (int i = lane; i < nc; i += 64) {
        unsigned long long ck = buf[wid][i];
        if (ck > key[K_TOP - 1]) {
            #pragma unroll
            for (int k = 0; k < K_TOP; ++k) {
                unsigned long long hi = key[k] > ck ? key[k] : ck;
                unsigned long long lo = key[k] > ck ? ck : key[k];
                key[k] = hi; ck = lo;
            }
        }
    }

    // 13-round 64-lane butterfly head-merge; >=32 candidates so no early-exit
    #pragma unroll 1
    for (int r = 0; r < K_TOP; ++r) {
        unsigned long long best = key[0];
        #pragma unroll
        for (int d = 1; d < 64; d <<= 1) {
            unsigned long long o = __shfl_xor(best, d, 64);
            best = o > best ? o : best;
        }
        if (key[0] == best && best != 0ull) {   // unique keys -> one winner
            #pragma unroll
            for (int k = 0; k < K_TOP - 1; ++k) key[k] = key[k + 1];
            key[K_TOP - 1] = 0ull;
        }
        if (lane == 0) {
            int win = 0xFFFF - (int)(best & 0xFFFFull);
            atomicOr(&posbits[((size_t)b * L_DIM + win) * 2 + (n >> 6)],
                     1ULL << (n & 63));
        }
    }
}

// K_assign: posbits & recomputed-spatial (set bits only); pcnt<=1 inline;
// pcnt>1 queued in LDS, resolved wave-cooperatively. Positive anchors append
// (bl<<7)|fin to the global positives list (consumed by k_out's scatter).
__global__ __launch_bounds__(256) void k_assign(
    const float* __restrict__ psc, const float* __restrict__ pbox,
    const float* __restrict__ pts,
    const int* __restrict__ glbl, const float* __restrict__ gbox,
    const unsigned long long* __restrict__ posbits,
    const int* __restrict__ bgp,
    float* __restrict__ out_lab, float* __restrict__ out_box,
    float* __restrict__ alat,
    float* __restrict__ maxal, float* __restrict__ maxio,
    int* __restrict__ pcount, int* __restrict__ plist)
{
    const int b = blockIdx.y, t = threadIdx.x;
    const int l = blockIdx.x * 256 + t;
    __shared__ float4 gb[N_DIM];
    __shared__ int    gl[N_DIM];
    __shared__ int    qlist[256];
    __shared__ unsigned long long qp0[256], qp1[256];
    __shared__ int    qn;
    if (t == 0) qn = 0;
    if (t < N_DIM) {
        gb[t] = reinterpret_cast<const float4*>(gbox)[(size_t)b * N_DIM + t];
        gl[t] = glbl[b * N_DIM + t];
    }
    __syncthreads();

    // ---- pass 1: per-thread; conflicted anchors deferred to LDS queue ----
    if (l < L_DIM) {
        const size_t bl = (size_t)b * L_DIM + l;
        const unsigned long long w0 = posbits[bl * 2 + 0];
        const unsigned long long w1 = posbits[bl * 2 + 1];
        unsigned long long p0 = 0ull, p1 = 0ull;
        if (w0 | w1) {                          // recompute spatial for set bits only
            const float2 ap = reinterpret_cast<const float2*>(pts)[l];
            unsigned long long m = w0;
            while (m) {
                int n = __ffsll((long long)m) - 1; m &= m - 1;
                float4 g = gb[n];
                if (ap.x >= g.x && ap.x <= g.z && ap.y >= g.y && ap.y <= g.w)
                    p0 |= 1ull << n;
            }
            m = w1;
            while (m) {
                int n = __ffsll((long long)m) - 1; m &= m - 1;
                float4 g = gb[n + 64];
                if (ap.x >= g.x && ap.x <= g.z && ap.y >= g.y && ap.y <= g.w)
                    p1 |= 1ull << n;
            }
        }
        const int pcnt = __popcll(p0) + __popcll(p1);

        if (pcnt <= 1) {
            int fin = (pcnt == 1) ? (p0 ? (__ffsll(p0) - 1) : (64 + __ffsll(p1) - 1)) : -1;
            __builtin_nontemporal_store((fin >= 0) ? (float)gl[fin] : (float)bgp[0], &out_lab[bl]);
            int gidx = (fin >= 0) ? fin : 0;      // ref gathers boxes with argmax=0 for bg
            nt_store4(gb[gidx], &reinterpret_cast<float4*>(out_box)[bl]);
            if (fin >= 0) {
                const float4 pb = reinterpret_cast<const float4*>(pbox)[bl];
                float4 g = gb[fin];
                float iou = iou_pair(g.x, g.y, g.z, g.w, pb.x, pb.y, pb.z, pb.w);
                int lb = min(max(gl[fin], 0), C_DIM - 1);
                float cs = psc[bl * C_DIM + lb];
                float al = cs * powf(iou, 6.0f);
                alat[bl] = al;
                // all values >= 0, init 0 -> int-compare == float-compare
                atomicMax((int*)&maxal[b * N_DIM + fin], __float_as_int(al));
                atomicMax((int*)&maxio[b * N_DIM + fin], __float_as_int(iou));
                int pi = atomicAdd(pcount, 1);
                if (pi < PLCAP) plist[pi] = ((int)bl << 7) | fin;
            }
        } else {
            int qi = atomicAdd(&qn, 1);
            qlist[qi] = l; qp0[qi] = p0; qp1[qi] = p1;
        }
    }
    __syncthreads();

    // ---- pass 2: wave-cooperative conflict resolution ----
    const int lane = t & 63, wid = t >> 6;
    const int nq = qn;
    for (int i = wid; i < nq; i += 4) {
        const int ql = qlist[i];
        const size_t bl = (size_t)b * L_DIM + ql;
        const float4 pb = reinterpret_cast<const float4*>(pbox)[bl];  // same addr, broadcast
        float4 gA = gb[lane];
        float4 gB = gb[lane + 64];
        float iouA = iou_pair(gA.x, gA.y, gA.z, gA.w, pb.x, pb.y, pb.z, pb.w);
        float iouB = iou_pair(gB.x, gB.y, gB.z, gB.w, pb.x, pb.y, pb.z, pb.w);
        unsigned long long kA = ((unsigned long long)__float_as_uint(iouA) << 32)
                              | (unsigned long long)(0xFFFFFFFFu - (unsigned)lane);
        unsigned long long kB = ((unsigned long long)__float_as_uint(iouB) << 32)
                              | (unsigned long long)(0xFFFFFFFFu - (unsigned)(lane + 64));
        unsigned long long k = kA > kB ? kA : kB;   // iou in [0,1] -> bits monotone
        #pragma unroll
        for (int d = 1; d < 64; d <<= 1) {
            unsigned long long o = __shfl_xor(k, d, 64);
            k = o > k ? o : k;
        }
        if (lane == 0) {
            int bestn = (int)(0xFFFFFFFFu - (unsigned)(k & 0xFFFFFFFFull));
            float bestiou = __uint_as_float((unsigned)(k >> 32));
            const unsigned long long p0 = qp0[i], p1 = qp1[i];
            bool posbest = (bestn < 64) ? ((p0 >> bestn) & 1ull) : ((p1 >> (bestn - 64)) & 1ull);
            int fin = posbest ? bestn : -1;
            __builtin_nontemporal_store((fin >= 0) ? (float)gl[fin] : (float)bgp[0], &out_lab[bl]);
            int gidx = (fin >= 0) ? fin : 0;
            nt_store4(gb[gidx], &reinterpret_cast<float4*>(out_box)[bl]);
            if (fin >= 0) {
                int lb = min(max(gl[fin], 0), C_DIM - 1);
                float cs = psc[bl * C_DIM + lb];
                float al = cs * powf(bestiou, 6.0f);
                alat[bl] = al;
                atomicMax((int*)&maxal[b * N_DIM + fin], __float_as_int(al));
                atomicMax((int*)&maxio[b * N_DIM + fin], __float_as_int(bestiou));
                int pi = atomicAdd(pcount, 1);
                if (pi < PLCAP) plist[pi] = ((int)bl << 7) | fin;
            }
        }
    }
}

// K_out: scatter the ~10k nonzero scores (bulk zeros written by k_push).
// One float store per positive anchor: out_sc[bl*80 + label] = norm.
__global__ __launch_bounds__(256) void k_out(
    const int* __restrict__ pcount, const int* __restrict__ plist,
    const float* __restrict__ alat,
    const float* __restrict__ maxal, const float* __restrict__ maxio,
    const int* __restrict__ glbl,
    float* __restrict__ outs)
{
    const int cnt = min(*pcount, PLCAP);
    for (int i = blockIdx.x * 256 + threadIdx.x; i < cnt; i += 64 * 256) {
        const int e = plist[i];
        const int fin = e & 127;
        const int bl = e >> 7;
        const int b = bl / L_DIM;
        float v = alat[bl] / (maxal[b * N_DIM + fin] + EPS_F) * maxio[b * N_DIM + fin];
        int cl = glbl[b * N_DIM + fin];
        if (cl >= 0 && cl < C_DIM)             // exact one_hot semantics
            outs[(size_t)bl * C_DIM + cl] = v;
    }
}

extern "C" void kernel_launch(void* const* d_in, const int* in_sizes, int n_in,
                              void* d_out, int out_size, void* d_ws, size_t ws_size,
                              hipStream_t stream)
{
    const float* psc  = (const float*)d_in[0];   // [B,L,C]
    const float* pbox = (const float*)d_in[1];   // [B,L,4]
    const float* pts  = (const float*)d_in[2];   // [1,L,2]
    const int*   glbl = (const int*)d_in[3];     // [B,N,1]
    const float* gbox = (const float*)d_in[4];   // [B,N,4]
    const float* gpad = (const float*)d_in[5];   // [B,N,1]
    const int*   bgp  = (const int*)d_in[6];     // scalar (=C)

    // workspace layout (16-byte aligned blocks)
    const size_t P = (size_t)B_DIM * L_DIM * 2 * sizeof(unsigned long long); // 4,300,800
    char* w = (char*)d_ws;
    unsigned long long* posbits = (unsigned long long*)w;                    // P bytes
    float* maxal = (float*)(w + P);                                          // 4096 B
    float* maxio = (float*)(w + P + 4096);                                   // 4096 B
    int*   scount = (int*) (w + P + 8192);                                   // 270,336 B
    float* alat  = (float*)(w + P + 8192 + 270336);                          // 1,075,200 B
    int*   pcount = (int*) (w + P + 8192 + 270336 + 1075200);                // 4096 B
    int*   plist  = (int*) (w + P + 8192 + 270336 + 1075200 + 4096);         // 65,536 B
    unsigned long long* bucket = (unsigned long long*)(w + P + 8192 + 270336 + 1075200 + 4096 + 65536); // 17.3 MB

    float* out_lab = (float*)d_out;                              // [B,L]
    float* out_box = out_lab + (size_t)B_DIM * L_DIM;            // [B,L,4]
    float* out_sc  = out_box + (size_t)B_DIM * L_DIM * 4;        // [B,L,C]

    // zeroing folded in: posbits + maxal/maxio + pcount + out_sc inside k_push;
    // scount fully rewritten every call; bucket read only up to scount.
    k_push<<<dim3(NCH2, B_DIM), dim3(256), 0, stream>>>(
        pts, pbox, gbox, gpad, glbl, psc, scount, bucket, (ulonglong2*)posbits,
        maxal, maxio, pcount, out_sc);
    k_top13<<<dim3(256), dim3(256), 0, stream>>>(
        psc, pbox, pts, glbl, gbox, gpad, scount, bucket, posbits);
    k_assign<<<dim3((L_DIM + 255) / 256, B_DIM), dim3(256), 0, stream>>>(
        psc, pbox, pts, glbl, gbox, posbits, bgp,
        out_lab, out_box, alat, maxal, maxio, pcount, plist);
    k_out<<<dim3(64), dim3(256), 0, stream>>>(
        pcount, plist, alat, maxal, maxio, glbl, out_sc);
}

// Round 19
// 74.897 us; speedup vs baseline: 1.3844x; 1.3844x over previous
//
#include <hip/hip_runtime.h>
#include <cstdint>
#include <cstddef>

#define B_DIM 8
#define L_DIM 33600
#define N_DIM 128
#define C_DIM 80
#define K_TOP 13
#define EPS_F 1e-9f
#define NCH2 66       // ceil(L_DIM/512): 512-anchor chunks (2 anchors/thread)
#define SEGSZ 32      // per-(bn,chunk) iou>0 entries
#define WBUF 352      // per-wave candidate buffer (max bn iou>0 ~270 +10sigma)

typedef float f32x4 __attribute__((ext_vector_type(4)));

// Bit-exact replica of the reference IoU (f32, no FMA contraction, same op order).
__device__ __forceinline__ float iou_pair(float g0, float g1, float g2, float g3,
                                          float p0, float p1, float p2, float p3) {
    float ltx = fmaxf(g0, p0), lty = fmaxf(g1, p1);
    float rbx = fminf(g2, p2), rby = fminf(g3, p3);
    float wx = fmaxf(__fsub_rn(rbx, ltx), 0.0f);
    float wy = fmaxf(__fsub_rn(rby, lty), 0.0f);
    float inter = __fmul_rn(wx, wy);
    float ag = __fmul_rn(__fsub_rn(g2, g0), __fsub_rn(g3, g1));
    float ap = __fmul_rn(__fsub_rn(p2, p0), __fsub_rn(p3, p1));
    float den = __fadd_rn(__fsub_rn(__fadd_rn(ag, ap), inter), EPS_F);
    float iou = __fdiv_rn(inter, den);
    if (iou > 1.0f) iou = 0.0f;            // (1.0 + 1e-9) rounds to 1.0f in f32
    iou = fminf(fmaxf(iou, 0.0f), 1.0f);
    return iou;
}

// Sortable key: (truncated double bits of s>=0) | (0xFFFF - l) in low 16.
__device__ __forceinline__ unsigned long long make_key(double s, int l) {
    unsigned long long sb = (unsigned long long)__double_as_longlong(s);
    return (sb & 0xFFFFFFFFFFFF0000ull) | (unsigned long long)(0xFFFF - l);
}

// K_push: 2 anchors/thread; padded GTs as inverted boxes; zeroes posbits
// slots; chunk-0 blocks zero maxal/maxio; single-walk segmented scatter.
// iou>0 filter: only pairs with iou>0 are scored+bucketed (zero-keys can
// never beat the 32 seed zero-keys downstream).
__global__ __launch_bounds__(256) void k_push(
    const float* __restrict__ pts, const float* __restrict__ pbox,
    const float* __restrict__ gbox, const float* __restrict__ gpad,
    const int* __restrict__ glbl, const float* __restrict__ psc,
    int* __restrict__ scount, unsigned long long* __restrict__ bucket,
    ulonglong2* __restrict__ posb2,
    float* __restrict__ maxal, float* __restrict__ maxio)
{
    const int chunk = blockIdx.x, b = blockIdx.y, t = threadIdx.x;
    __shared__ float4 gb[N_DIM];
    __shared__ int    gli[N_DIM];
    __shared__ int    lcnt[N_DIM];
    if (t < N_DIM) {
        float4 g = reinterpret_cast<const float4*>(gbox)[(size_t)b * N_DIM + t];
        if (gpad[b * N_DIM + t] <= 0.0f) g = make_float4(3e38f, 3e38f, -3e38f, -3e38f);
        gb[t] = g;
        gli[t] = min(max(glbl[b * N_DIM + t], 0), C_DIM - 1);
        lcnt[t] = 0;
        if (chunk == 0) { maxal[b * N_DIM + t] = 0.0f; maxio[b * N_DIM + t] = 0.0f; }
    }
    __syncthreads();

    const float* psb = psc + (size_t)b * L_DIM * C_DIM;
    const float4* pbb = reinterpret_cast<const float4*>(pbox) + (size_t)b * L_DIM;
    const int l0 = chunk * 512 + t, l1 = l0 + 256;
    const bool v0 = (l0 < L_DIM), v1 = (l1 < L_DIM);
    float a0x = -3e38f, a0y = -3e38f, a1x = -3e38f, a1y = -3e38f;
    float4 pb0 = make_float4(0, 0, 0, 0), pb1 = make_float4(0, 0, 0, 0);
    if (v0) {
        posb2[(size_t)b * L_DIM + l0] = make_ulonglong2(0ull, 0ull);
        const float2 ap = reinterpret_cast<const float2*>(pts)[l0];
        a0x = ap.x; a0y = ap.y;
        pb0 = pbb[l0];                        // coalesced float4
    }
    if (v1) {
        posb2[(size_t)b * L_DIM + l1] = make_ulonglong2(0ull, 0ull);
        const float2 ap = reinterpret_cast<const float2*>(pts)[l1];
        a1x = ap.x; a1y = ap.y;
        pb1 = pbb[l1];
    }

    unsigned long long m0a = 0ull, m1a = 0ull, m0b = 0ull, m1b = 0ull;
    for (int n = 0; n < N_DIM; ++n) {
        const float4 g = gb[n];
        bool i0 = (a0x >= g.x && a0x <= g.z && a0y >= g.y && a0y <= g.w);
        bool i1 = (a1x >= g.x && a1x <= g.z && a1y >= g.y && a1y <= g.w);
        if (n < 64) { m0a |= i0 ? (1ull << n) : 0ull;        m0b |= i1 ? (1ull << n) : 0ull; }
        else        { m1a |= i0 ? (1ull << (n - 64)) : 0ull; m1b |= i1 ? (1ull << (n - 64)) : 0ull; }
    }

    const size_t segbase = ((size_t)(b * N_DIM) * NCH2 + chunk) * SEGSZ;
    if (v0 && l0 >= 32) {                      // l<32 are unconditional seeds downstream
        unsigned long long m = m0a;
        while (m) {
            int n = __ffsll((long long)m) - 1; m &= m - 1;
            const float4 g = gb[n];
            float iou = iou_pair(g.x, g.y, g.z, g.w, pb0.x, pb0.y, pb0.z, pb0.w);
            if (iou > 0.0f) {
                float cs = psb[(size_t)l0 * C_DIM + gli[n]];
                double d = (double)iou, d2 = d * d;
                unsigned long long key = make_key((double)cs * (d2 * d2 * d2), l0);
                int pos = atomicAdd(&lcnt[n], 1);
                if (pos < SEGSZ) bucket[segbase + (size_t)n * NCH2 * SEGSZ + pos] = key;
            }
        }
        m = m1a;
        while (m) {
            int n = __ffsll((long long)m) - 1; m &= m - 1;
            const float4 g = gb[n + 64];
            float iou = iou_pair(g.x, g.y, g.z, g.w, pb0.x, pb0.y, pb0.z, pb0.w);
            if (iou > 0.0f) {
                float cs = psb[(size_t)l0 * C_DIM + gli[n + 64]];
                double d = (double)iou, d2 = d * d;
                unsigned long long key = make_key((double)cs * (d2 * d2 * d2), l0);
                int pos = atomicAdd(&lcnt[n + 64], 1);
                if (pos < SEGSZ) bucket[segbase + (size_t)(n + 64) * NCH2 * SEGSZ + pos] = key;
            }
        }
    }
    if (v1) {                                  // l1 >= 256 always
        unsigned long long m = m0b;
        while (m) {
            int n = __ffsll((long long)m) - 1; m &= m - 1;
            const float4 g = gb[n];
            float iou = iou_pair(g.x, g.y, g.z, g.w, pb1.x, pb1.y, pb1.z, pb1.w);
            if (iou > 0.0f) {
                float cs = psb[(size_t)l1 * C_DIM + gli[n]];
                double d = (double)iou, d2 = d * d;
                unsigned long long key = make_key((double)cs * (d2 * d2 * d2), l1);
                int pos = atomicAdd(&lcnt[n], 1);
                if (pos < SEGSZ) bucket[segbase + (size_t)n * NCH2 * SEGSZ + pos] = key;
            }
        }
        m = m1b;
        while (m) {
            int n = __ffsll((long long)m) - 1; m &= m - 1;
            const float4 g = gb[n + 64];
            float iou = iou_pair(g.x, g.y, g.z, g.w, pb1.x, pb1.y, pb1.z, pb1.w);
            if (iou > 0.0f) {
                float cs = psb[(size_t)l1 * C_DIM + gli[n + 64]];
                double d = (double)iou, d2 = d * d;
                unsigned long long key = make_key((double)cs * (d2 * d2 * d2), l1);
                int pos = atomicAdd(&lcnt[n + 64], 1);
                if (pos < SEGSZ) bucket[segbase + (size_t)(n + 64) * NCH2 * SEGSZ + pos] = key;
            }
        }
    }
    __syncthreads();

    if (t < N_DIM)                             // counts written every call (no zeroing)
        scount[(b * N_DIM + t) * NCH2 + chunk] = min(lcnt[t], SEGSZ);
}

// K_top13: ONE WAVE per (b,n), 4 bn per 256-thread block, grid 256.
// Compact this bn's ~27 segment entries into a per-wave LDS buffer, then
// per-lane 13-deep lists + 13-round 64-lane butterfly; lane 0 atomicOr.
__global__ __launch_bounds__(256) void k_top13(
    const float* __restrict__ psc, const float* __restrict__ pbox,
    const float* __restrict__ pts, const int* __restrict__ glbl,
    const float* __restrict__ gbox, const float* __restrict__ gpad,
    const int* __restrict__ scount, const unsigned long long* __restrict__ bucket,
    unsigned long long* __restrict__ posbits)
{
    const int t = threadIdx.x, lane = t & 63, wid = t >> 6;
    const int bn = blockIdx.x * 4 + wid;        // grid 256 -> bn 0..1023
    const int b = bn >> 7, n = bn & 127;
    const bool active = (gpad[b * N_DIM + n] > 0.0f);

    __shared__ unsigned long long buf[4][WBUF];
    __shared__ int wq[4];
    if (lane == 0) wq[wid] = 0;
    __builtin_amdgcn_wave_barrier();

    if (active) {                               // phase 1: compact segments
        for (int s = lane; s < NCH2; s += 64) {
            int c = scount[bn * NCH2 + s];
            if (c > 0) {
                int pos = atomicAdd(&wq[wid], c);
                const unsigned long long* seg = bucket + ((size_t)bn * NCH2 + s) * SEGSZ;
                for (int j = 0; j < c; ++j)
                    if (pos + j < WBUF) buf[wid][pos + j] = seg[j];
            }
        }
    }
    __syncthreads();                            // all waves participate exactly once
    if (!active) return;

    const int nc = min(wq[wid], WBUF);
    const float g0 = gbox[(b * N_DIM + n) * 4 + 0];
    const float g1 = gbox[(b * N_DIM + n) * 4 + 1];
    const float g2 = gbox[(b * N_DIM + n) * 4 + 2];
    const float g3 = gbox[(b * N_DIM + n) * 4 + 3];
    int lbl = glbl[b * N_DIM + n];
    lbl = min(max(lbl, 0), C_DIM - 1);
    const float* psb = psc + (size_t)b * L_DIM * C_DIM;
    const float* pbb = pbox + (size_t)b * L_DIM * 4;

    unsigned long long key[K_TOP];
    #pragma unroll
    for (int k = 0; k < K_TOP; ++k) key[k] = 0ull;

    // seed candidate (lane < 32): full scoring path for l = lane
    if (lane < 32) {
        const int l = lane;
        const float2 ap = reinterpret_cast<const float2*>(pts)[l];
        unsigned long long ck = (unsigned long long)(0xFFFF - l);
        if (ap.x >= g0 && ap.x <= g2 && ap.y >= g1 && ap.y <= g3) {
            const float4 pbv = reinterpret_cast<const float4*>(pbb)[l];
            float iou = iou_pair(g0, g1, g2, g3, pbv.x, pbv.y, pbv.z, pbv.w);
            if (iou > 0.0f) {
                float cs = psb[(size_t)l * C_DIM + lbl];
                double d = (double)iou, d2 = d * d;
                ck = make_key((double)cs * (d2 * d2 * d2), l);
            }
        }
        key[0] = ck;                            // list was empty; sorted trivially
    }
    // bucket candidates: one per lane per pass (~27 total -> 1 pass typical)
    for (int i = lane; i < nc; i += 64) {
        unsigned long long ck = buf[wid][i];
        if (ck > key[K_TOP - 1]) {
            #pragma unroll
            for (int k = 0; k < K_TOP; ++k) {
                unsigned long long hi = key[k] > ck ? key[k] : ck;
                unsigned long long lo = key[k] > ck ? ck : key[k];
                key[k] = hi; ck = lo;
            }
        }
    }

    // 13-round 64-lane butterfly head-merge; >=32 candidates so no early-exit
    #pragma unroll 1
    for (int r = 0; r < K_TOP; ++r) {
        unsigned long long best = key[0];
        #pragma unroll
        for (int d = 1; d < 64; d <<= 1) {
            unsigned long long o = __shfl_xor(best, d, 64);
            best = o > best ? o : best;
        }
        if (key[0] == best && best != 0ull) {   // unique keys -> one winner
            #pragma unroll
            for (int k = 0; k < K_TOP - 1; ++k) key[k] = key[k + 1];
            key[K_TOP - 1] = 0ull;
        }
        if (lane == 0) {
            int win = 0xFFFF - (int)(best & 0xFFFFull);
            atomicOr(&posbits[((size_t)b * L_DIM + win) * 2 + (n >> 6)],
                     1ULL << (n & 63));
        }
    }
}

// K_assign: posbits & recomputed-spatial (set bits only); pcnt<=1 inline;
// pcnt>1 queued in LDS, resolved wave-cooperatively (64 lanes x 2 ious +
// u64 shfl max-reduce; first-max tie semantics). Regular stores (L3-absorbed).
__global__ __launch_bounds__(256) void k_assign(
    const float* __restrict__ psc, const float* __restrict__ pbox,
    const float* __restrict__ pts,
    const int* __restrict__ glbl, const float* __restrict__ gbox,
    const unsigned long long* __restrict__ posbits,
    const int* __restrict__ bgp,
    float* __restrict__ out_lab, float* __restrict__ out_box,
    int* __restrict__ fin_out, float* __restrict__ alat,
    float* __restrict__ maxal, float* __restrict__ maxio)
{
    const int b = blockIdx.y, t = threadIdx.x;
    const int l = blockIdx.x * 256 + t;
    __shared__ float4 gb[N_DIM];
    __shared__ int    gl[N_DIM];
    __shared__ int    qlist[256];
    __shared__ unsigned long long qp0[256], qp1[256];
    __shared__ int    qn;
    if (t == 0) qn = 0;
    if (t < N_DIM) {
        gb[t] = reinterpret_cast<const float4*>(gbox)[(size_t)b * N_DIM + t];
        gl[t] = glbl[b * N_DIM + t];
    }
    __syncthreads();

    // ---- pass 1: per-thread; conflicted anchors deferred to LDS queue ----
    if (l < L_DIM) {
        const size_t bl = (size_t)b * L_DIM + l;
        const unsigned long long w0 = posbits[bl * 2 + 0];
        const unsigned long long w1 = posbits[bl * 2 + 1];
        unsigned long long p0 = 0ull, p1 = 0ull;
        if (w0 | w1) {                          // recompute spatial for set bits only
            const float2 ap = reinterpret_cast<const float2*>(pts)[l];
            unsigned long long m = w0;
            while (m) {
                int n = __ffsll((long long)m) - 1; m &= m - 1;
                float4 g = gb[n];
                if (ap.x >= g.x && ap.x <= g.z && ap.y >= g.y && ap.y <= g.w)
                    p0 |= 1ull << n;
            }
            m = w1;
            while (m) {
                int n = __ffsll((long long)m) - 1; m &= m - 1;
                float4 g = gb[n + 64];
                if (ap.x >= g.x && ap.x <= g.z && ap.y >= g.y && ap.y <= g.w)
                    p1 |= 1ull << n;
            }
        }
        const int pcnt = __popcll(p0) + __popcll(p1);

        if (pcnt <= 1) {
            int fin = (pcnt == 1) ? (p0 ? (__ffsll(p0) - 1) : (64 + __ffsll(p1) - 1)) : -1;
            out_lab[bl] = (fin >= 0) ? (float)gl[fin] : (float)bgp[0];
            int gidx = (fin >= 0) ? fin : 0;      // ref gathers boxes with argmax=0 for bg
            reinterpret_cast<float4*>(out_box)[bl] = gb[gidx];
            fin_out[bl] = fin;
            if (fin >= 0) {
                const float4 pb = reinterpret_cast<const float4*>(pbox)[bl];
                float4 g = gb[fin];
                float iou = iou_pair(g.x, g.y, g.z, g.w, pb.x, pb.y, pb.z, pb.w);
                int lb = min(max(gl[fin], 0), C_DIM - 1);
                float cs = psc[bl * C_DIM + lb];
                float al = cs * powf(iou, 6.0f);
                alat[bl] = al;
                // all values >= 0, init 0 -> int-compare == float-compare
                atomicMax((int*)&maxal[b * N_DIM + fin], __float_as_int(al));
                atomicMax((int*)&maxio[b * N_DIM + fin], __float_as_int(iou));
            }
        } else {
            int qi = atomicAdd(&qn, 1);
            qlist[qi] = l; qp0[qi] = p0; qp1[qi] = p1;
        }
    }
    __syncthreads();

    // ---- pass 2: wave-cooperative conflict resolution ----
    const int lane = t & 63, wid = t >> 6;
    const int nq = qn;
    for (int i = wid; i < nq; i += 4) {
        const int ql = qlist[i];
        const size_t bl = (size_t)b * L_DIM + ql;
        const float4 pb = reinterpret_cast<const float4*>(pbox)[bl];  // same addr, broadcast
        float4 gA = gb[lane];
        float4 gB = gb[lane + 64];
        float iouA = iou_pair(gA.x, gA.y, gA.z, gA.w, pb.x, pb.y, pb.z, pb.w);
        float iouB = iou_pair(gB.x, gB.y, gB.z, gB.w, pb.x, pb.y, pb.z, pb.w);
        unsigned long long kA = ((unsigned long long)__float_as_uint(iouA) << 32)
                              | (unsigned long long)(0xFFFFFFFFu - (unsigned)lane);
        unsigned long long kB = ((unsigned long long)__float_as_uint(iouB) << 32)
                              | (unsigned long long)(0xFFFFFFFFu - (unsigned)(lane + 64));
        unsigned long long k = kA > kB ? kA : kB;   // iou in [0,1] -> bits monotone
        #pragma unroll
        for (int d = 1; d < 64; d <<= 1) {
            unsigned long long o = __shfl_xor(k, d, 64);
            k = o > k ? o : k;
        }
        if (lane == 0) {
            int bestn = (int)(0xFFFFFFFFu - (unsigned)(k & 0xFFFFFFFFull));
            float bestiou = __uint_as_float((unsigned)(k >> 32));
            const unsigned long long p0 = qp0[i], p1 = qp1[i];
            bool posbest = (bestn < 64) ? ((p0 >> bestn) & 1ull) : ((p1 >> (bestn - 64)) & 1ull);
            int fin = posbest ? bestn : -1;
            out_lab[bl] = (fin >= 0) ? (float)gl[fin] : (float)bgp[0];
            int gidx = (fin >= 0) ? fin : 0;
            reinterpret_cast<float4*>(out_box)[bl] = gb[gidx];
            fin_out[bl] = fin;
            if (fin >= 0) {
                int lb = min(max(gl[fin], 0), C_DIM - 1);
                float cs = psc[bl * C_DIM + lb];
                float al = cs * powf(bestiou, 6.0f);
                alat[bl] = al;
                atomicMax((int*)&maxal[b * N_DIM + fin], __float_as_int(al));
                atomicMax((int*)&maxio[b * N_DIM + fin], __float_as_int(bestiou));
            }
        }
    }
}

// K_out: fused norm + one-hot score fill, REGULAR float4 stores (86MB fits
// the 256MB L3; kernel completes at L3 visibility — no forced HBM round-trip
// like nontemporal. Last kernel, so no cache-pollution concern).
// Grid-stride over 16-anchor tiles (2048 blocks).
__global__ __launch_bounds__(256) void k_out(
    const int* __restrict__ fin_out, const float* __restrict__ alat,
    const float* __restrict__ maxal, const float* __restrict__ maxio,
    const int* __restrict__ glbl,
    float* __restrict__ outs)
{
    const int APB = 16;
    const int NTILES = (B_DIM * L_DIM + APB - 1) / APB;
    const int t = threadIdx.x;
    __shared__ float snf[APB];
    __shared__ int   scl[APB];
    float4* out4 = reinterpret_cast<float4*>(outs);

    for (int tile = blockIdx.x; tile < NTILES; tile += 2048) {
        const int a0 = tile * APB;
        __syncthreads();                       // protect snf/scl reuse
        if (t < APB) {
            int a = a0 + t;
            float v = 0.0f; int c = -1;
            if (a < B_DIM * L_DIM) {
                int b = a / L_DIM;
                int fin = fin_out[a];
                if (fin >= 0) {
                    v = alat[a] / (maxal[b * N_DIM + fin] + EPS_F) * maxio[b * N_DIM + fin];
                    c = glbl[b * N_DIM + fin];
                }
            }
            snf[t] = v; scl[t] = c;
        }
        __syncthreads();
        for (int j = t; j < APB * 20; j += 256) {
            int ai = j / 20;                   // anchor within tile
            int a = a0 + ai;
            if (a >= B_DIM * L_DIM) continue;
            int c0 = (j - ai * 20) * 4;
            float v = snf[ai]; int cl = scl[ai];
            float4 o;
            o.x = (c0 + 0 == cl) ? v : 0.0f;
            o.y = (c0 + 1 == cl) ? v : 0.0f;
            o.z = (c0 + 2 == cl) ? v : 0.0f;
            o.w = (c0 + 3 == cl) ? v : 0.0f;
            out4[(size_t)a * 20 + (j - ai * 20)] = o;
        }
    }
}

extern "C" void kernel_launch(void* const* d_in, const int* in_sizes, int n_in,
                              void* d_out, int out_size, void* d_ws, size_t ws_size,
                              hipStream_t stream)
{
    const float* psc  = (const float*)d_in[0];   // [B,L,C]
    const float* pbox = (const float*)d_in[1];   // [B,L,4]
    const float* pts  = (const float*)d_in[2];   // [1,L,2]
    const int*   glbl = (const int*)d_in[3];     // [B,N,1]
    const float* gbox = (const float*)d_in[4];   // [B,N,4]
    const float* gpad = (const float*)d_in[5];   // [B,N,1]
    const int*   bgp  = (const int*)d_in[6];     // scalar (=C)

    // workspace layout (16-byte aligned blocks)
    const size_t P = (size_t)B_DIM * L_DIM * 2 * sizeof(unsigned long long); // 4,300,800
    char* w = (char*)d_ws;
    unsigned long long* posbits = (unsigned long long*)w;                    // P bytes
    float* maxal = (float*)(w + P);                                          // 4096 B
    float* maxio = (float*)(w + P + 4096);                                   // 4096 B
    int*   scount = (int*) (w + P + 8192);                                   // 270,336 B
    int*   fin   = (int*)  (w + P + 8192 + 270336);                          // 1,075,200 B
    float* alat  = (float*)(w + P + 8192 + 270336 + 1075200);                // 1,075,200 B
    unsigned long long* bucket = (unsigned long long*)(w + P + 8192 + 270336 + 2 * 1075200); // 17.3 MB

    float* out_lab = (float*)d_out;                              // [B,L]
    float* out_box = out_lab + (size_t)B_DIM * L_DIM;            // [B,L,4]
    float* out_sc  = out_box + (size_t)B_DIM * L_DIM * 4;        // [B,L,C]

    // zeroing folded in: posbits + maxal/maxio inside k_push; scount fully
    // rewritten every call; bucket read only up to scount. 4 graph nodes.
    k_push<<<dim3(NCH2, B_DIM), dim3(256), 0, stream>>>(
        pts, pbox, gbox, gpad, glbl, psc, scount, bucket, (ulonglong2*)posbits, maxal, maxio);
    k_top13<<<dim3(256), dim3(256), 0, stream>>>(
        psc, pbox, pts, glbl, gbox, gpad, scount, bucket, posbits);
    k_assign<<<dim3((L_DIM + 255) / 256, B_DIM), dim3(256), 0, stream>>>(
        psc, pbox, pts, glbl, gbox, posbits, bgp,
        out_lab, out_box, fin, alat, maxal, maxio);
    k_out<<<dim3(2048), dim3(256), 0, stream>>>(
        fin, alat, maxal, maxio, glbl, out_sc);
}